// Round 10
// baseline (1824.003 us; speedup 1.0000x reference)
//
#include <hip/hip_runtime.h>
#include <math.h>

typedef unsigned long long u64;
typedef unsigned int u32;

#define BN 32
#define TN 128
#define ENCD 1024
#define HID 320
#define NG 1280       // 4*HID
#define VN 29
#define BLANKI 28
#define SLICES 8
#define UPS 40        // hidden units per slice
#define ROWS 160      // gate rows per slice (4*UPS)
#define JW 1344       // ENC+HID
#define XSTRIDE 48    // u64 words per (parity,b,slice) region; 40 used
#define NPOLL (7*UPS) // 280 h2 words polled per step by waves 1-3

// workspace layout (floats)
#define E_OFF   0
#define E_SZ    (TN*BN*VN)          // 118784
#define P_OFF   (E_OFF + E_SZ)
#define P_SZ    (VN*NG)             // 37120
#define X_OFF   (P_OFF + P_SZ)      // byte 623616, 16B aligned
#define X_U64S  (2*BN*SLICES*XSTRIDE)   // 24576 u64

__device__ __forceinline__ float dot4(float4 a, float4 b) {
    return a.x*b.x + a.y*b.y + a.z*b.z + a.w*b.w;
}
__device__ __forceinline__ u64 aload(const u64* p) {
    return __hip_atomic_load(p, __ATOMIC_RELAXED, __HIP_MEMORY_SCOPE_AGENT);
}
__device__ __forceinline__ void astore(u64* p, u64 v) {
    __hip_atomic_store(p, v, __ATOMIC_RELAXED, __HIP_MEMORY_SCOPE_AGENT);
}

// K1: E[t][b][v] = b_joint[v] + x[t][b][:1024] . W_joint[v][:1024]; zeroes xchg.
__global__ __launch_bounds__(256) void k_enc(const float* __restrict__ x,
        const float* __restrict__ Wj, const float* __restrict__ bj,
        float* __restrict__ E, u64* __restrict__ xchg)
{
    __shared__ float xl[4][1056];
    const int tid = threadIdx.x;
    const int blk = blockIdx.x;
    const int t = blk >> 3, b0 = (blk & 7) * 4;

    if (tid < 24) xchg[(size_t)blk*24 + tid] = 0ull;   // 1024*24 == X_U64S

    #pragma unroll
    for (int bb = 0; bb < 4; ++bb) {
        const float4* src = (const float4*)(x + ((size_t)(t*BN + b0 + bb))*ENCD);
        float4 v4 = src[tid];
        ((float4*)&xl[bb][0])[tid + (tid >> 5)] = v4;
    }
    __syncthreads();
    if (tid < 232) {
        const int v = tid >> 3, k8 = tid & 7;
        float a0=0.f, a1=0.f, a2=0.f, a3=0.f;
        const float4* wrow = (const float4*)(Wj + (size_t)v*JW) + k8*32;
        const float4* x0 = ((const float4*)&xl[0][0]) + k8*33;
        const float4* x1 = ((const float4*)&xl[1][0]) + k8*33;
        const float4* x2 = ((const float4*)&xl[2][0]) + k8*33;
        const float4* x3 = ((const float4*)&xl[3][0]) + k8*33;
        #pragma unroll 4
        for (int m = 0; m < 32; ++m) {
            float4 w4 = wrow[m];
            a0 += dot4(w4, x0[m]);
            a1 += dot4(w4, x1[m]);
            a2 += dot4(w4, x2[m]);
            a3 += dot4(w4, x3[m]);
        }
        #pragma unroll
        for (int d = 1; d < 8; d <<= 1) {
            a0 += __shfl_xor(a0, d); a1 += __shfl_xor(a1, d);
            a2 += __shfl_xor(a2, d); a3 += __shfl_xor(a3, d);
        }
        if (k8 == 0) {
            float bjv = bj[v];
            E[((size_t)(t*BN + b0+0))*VN + v] = a0 + bjv;
            E[((size_t)(t*BN + b0+1))*VN + v] = a1 + bjv;
            E[((size_t)(t*BN + b0+2))*VN + v] = a2 + bjv;
            E[((size_t)(t*BN + b0+3))*VN + v] = a3 + bjv;
        }
    }
}

// K2: P[j][g] = b_ih[g]+b_hh[g] + emb[j] . W_ih[g]  (j==28 -> bias only / SOS)
__global__ __launch_bounds__(256) void k_pred(const float* __restrict__ emb,
        const float* __restrict__ Wih, const float* __restrict__ bih,
        const float* __restrict__ bhh, float* __restrict__ P)
{
    __shared__ float el[HID];
    const int tid = threadIdx.x, j = blockIdx.x;
    if (tid < 80) {
        float4 v4 = make_float4(0.f, 0.f, 0.f, 0.f);
        if (j < 28) v4 = ((const float4*)(emb + (size_t)j*HID))[tid];
        ((float4*)el)[tid] = v4;
    }
    __syncthreads();
    #pragma unroll
    for (int q = 0; q < 5; ++q) {
        const int r = q*256 + tid;
        float acc = bih[r] + bhh[r];
        const float4* wrow = (const float4*)(Wih + (size_t)r*HID);
        #pragma unroll 8
        for (int k4 = 0; k4 < 80; ++k4)
            acc += dot4(wrow[k4], ((const float4*)el)[k4]);
        P[(size_t)j*NG + r] = acc;
    }
}

// K3: greedy decode. 8 WGs per batch element; h2-ONLY tagged agent-scope
// exchange. Each WG re-derives the FULL joint locally from h2 (weights in
// registers, bit-identical reduction order). Waves 1-3 poll; wave 0 publishes.
__global__ __launch_bounds__(256, 1) void k_dec(const int* __restrict__ lengths,
        const float* __restrict__ Whh, const float* __restrict__ Wj,
        const float* __restrict__ E, const float* __restrict__ P,
        u64* __restrict__ xchg, float* __restrict__ out)
{
    __shared__ float P_lds[VN*ROWS];    // 18560 B
    __shared__ float h2st[HID];
    __shared__ float c2st[UPS];
    __shared__ float gates[ROWS];
    __shared__ float lsum[32];
    __shared__ float pad_force[15500];  // total LDS > 80KB -> 1 WG/CU

    const int tid = threadIdx.x;
    const int bid = blockIdx.x;
    const int b = bid & 31, slice = bid >> 5;
    const int rg = tid >> 3, kg = tid & 7;
    const int lane = tid & 63;

    int len = lengths[b];
    if (len > TN) len = TN;
    if (len < 0) {  // never true; keeps pad_force allocated
        pad_force[tid] = (float)tid;
        gates[tid & 127] = pad_force[(tid*7) & 15499];
    }

    // --- W_hh slice into registers: 5 rows x 40 cols per thread ---
    float4 wq[50];
    #pragma unroll
    for (int q = 0; q < 5; ++q) {
        const int r = rg*5 + q;
        const int gt = r / 40, u = r - gt*40;
        const float4* wrow = (const float4*)(Whh + ((size_t)(gt*HID + slice*UPS + u))*HID + kg*40);
        #pragma unroll
        for (int jb = 0; jb < 10; ++jb) wq[q*10 + jb] = wrow[jb];
    }
    for (int i = tid; i < VN*ROWS; i += 256) {
        const int jj = i / ROWS, r = i - jj*ROWS;
        const int gt = r / 40, u = r - gt*40;
        P_lds[i] = P[(size_t)jj*NG + gt*HID + slice*UPS + u];
    }
    // --- full joint hidden weights into registers: 40 scalars (tid<232) ---
    float wjr[40];
    if (tid < 232) {
        const int v = tid >> 3, k8 = tid & 7;
        const float* wv = Wj + (size_t)v*JW + ENCD + k8*5;
        #pragma unroll
        for (int j2 = 0; j2 < 8; ++j2)
            #pragma unroll
            for (int m2 = 0; m2 < 5; ++m2)
                wjr[j2*5 + m2] = wv[j2*40 + m2];
    } else {
        #pragma unroll
        for (int i = 0; i < 40; ++i) wjr[i] = 0.f;
    }
    if (tid < UPS) c2st[tid] = 0.f;
    if (slice == 0) for (int i = tid; i < 512; i += 256) out[b*512 + i] = -1.0f;
    __syncthreads();

    float lps = 0.f;
    float acc[5] = {0.f, 0.f, 0.f, 0.f, 0.f};   // = W_hh . h  (h starts at 0)
    float lsum_r = 0.f;                          // joint hidden sum for lane v
    int pos = 0, jrow = 28, n = 1;    // full-step sequence (0 = invalid tag)
    bool dirty = true;

    // --- poll assignment (waves 1-3): word1 = tid-64, word2 = tid-64+192 ---
    const int pw1 = tid - 64;
    const bool isPoller = (pw1 >= 0);
    const bool has2 = isPoller && (pw1 < NPOLL - 192);   // 88 threads carry 2nd

    for (int t = 0; t < len; ++t) {
        const float Ereg = (lane < VN)
            ? E[((size_t)(t*BN + b))*VN + lane] : -INFINITY;

        for (int s = 0; s < 4; ++s) {
            if (dirty) {
                // ================= FULL STEP =================
                const int par = n & 1;
                const size_t mybase = ((size_t)(par*BN + b)*SLICES + slice)*XSTRIDE;
                // gates = cached acc + P[jrow]
                if (kg == 0) {
                    #pragma unroll
                    for (int q = 0; q < 5; ++q) {
                        const int r = rg*5 + q;
                        gates[r] = acc[q] + P_lds[jrow*ROWS + r];
                    }
                }
                __syncthreads();   // B_gates
                if (tid < 64) {
                    // ---------- publisher wave: nonlin -> immediate h2 stores ----------
                    if (tid < UPS) {
                        const float gi = gates[tid],      gf = gates[40+tid];
                        const float gg = gates[80+tid],   go = gates[120+tid];
                        const float ii = 1.f/(1.f+expf(-gi));
                        const float ff = 1.f/(1.f+expf(-gf));
                        const float oo = 1.f/(1.f+expf(-go));
                        const float G  = tanhf(gg);
                        const float c2 = ff*c2st[tid] + ii*G;
                        c2st[tid] = c2;
                        const float h2 = oo * tanhf(c2);
                        h2st[slice*UPS + tid] = h2;
                        const u64 pk = ((u64)(u32)n << 32) | (u64)__float_as_uint(h2);
                        astore(&xchg[mybase + tid], pk);
                    }
                } else {
                    // ---------- poller waves 1-3: 280 peer h2 words ----------
                    const size_t pbase = ((size_t)(par*BN + b)*SLICES)*XSTRIDE;
                    int j1 = pw1 / UPS; const int w1 = pw1 - j1*UPS;
                    j1 += (j1 >= slice);
                    const u64* p1 = &xchg[pbase + (size_t)j1*XSTRIDE + w1];
                    bool need1 = true, need2 = has2;
                    int j2_ = 0, w2 = 0; const u64* p2 = p1;
                    if (has2) {
                        const int i2 = pw1 + 192;
                        j2_ = i2 / UPS; w2 = i2 - j2_*UPS;
                        j2_ += (j2_ >= slice);
                        p2 = &xchg[pbase + (size_t)j2_*XSTRIDE + w2];
                    }
                    int cap = 0;
                    while ((need1 | need2) && cap < (1 << 16)) {
                        u64 v1 = 0, v2 = 0;
                        if (need1) v1 = aload(p1);
                        if (need2) v2 = aload(p2);
                        if (need1 && (u32)(v1 >> 32) == (u32)n) {
                            h2st[j1*UPS + w1] = __uint_as_float((u32)v1);
                            need1 = false;
                        }
                        if (need2 && (u32)(v2 >> 32) == (u32)n) {
                            h2st[j2_*UPS + w2] = __uint_as_float((u32)v2);
                            need2 = false;
                        }
                        ++cap;
                    }
                }
                __syncthreads();   // B_poll: full h2st ready
                // ---- full joint locally (bit-identical order, weights in regs) ----
                if (tid < 232) {
                    const int v = tid >> 3, k8 = tid & 7;
                    float sA = 0.f;
                    #pragma unroll
                    for (int j2 = 0; j2 < 8; ++j2) {
                        float pk = 0.f;
                        #pragma unroll
                        for (int m2 = 0; m2 < 5; ++m2)
                            pk += wjr[j2*5 + m2] * h2st[j2*UPS + k8*5 + m2];
                        pk += __shfl_xor(pk, 1);
                        pk += __shfl_xor(pk, 2);
                        pk += __shfl_xor(pk, 4);
                        sA += pk;
                    }
                    if (k8 == 0) lsum[v] = sA;
                }
                // ---- speculative matvec for the NEXT full step ----
                {
                    float a2[5] = {0.f, 0.f, 0.f, 0.f, 0.f};
                    #pragma unroll
                    for (int jb = 0; jb < 10; ++jb) {
                        float4 hv = *(const float4*)(h2st + kg*40 + jb*4);
                        #pragma unroll
                        for (int q = 0; q < 5; ++q) a2[q] += dot4(wq[q*10 + jb], hv);
                    }
                    #pragma unroll
                    for (int q = 0; q < 5; ++q) {
                        a2[q] += __shfl_xor(a2[q], 1);
                        a2[q] += __shfl_xor(a2[q], 2);
                        a2[q] += __shfl_xor(a2[q], 4);
                        acc[q] = a2[q];
                    }
                }
                __syncthreads();   // B_lsum: lsum ready
                lsum_r = (lane < VN) ? lsum[lane] : 0.f;
                n++;
            }
            // ============ logits -> argmax -> update ============
            const float Lv = (lane < VN) ? (Ereg + lsum_r) : -INFINITY;
            float m = Lv; int ai = lane;
            #pragma unroll
            for (int d = 1; d < 64; d <<= 1) {
                const float om = __shfl_xor(m, d);
                const int   oi = __shfl_xor(ai, d);
                if (om > m || (om == m && oi < ai)) { m = om; ai = oi; }
            }
            float e = (lane < VN) ? expf(Lv - m) : 0.f;
            #pragma unroll
            for (int d = 1; d < 64; d <<= 1) e += __shfl_xor(e, d);
            lps += -logf(e);                 // v = logits[argmax] - lse

            if (ai == BLANKI) { dirty = false; break; }
            if (slice == 0 && tid == 0) out[b*512 + pos] = (float)ai;
            pos++;
            jrow = ai;
            dirty = true;
        }
    }

    if (slice == 0 && tid == 0) {
        out[16384 + b] = (float)pos;   // n_symbols
        out[16416 + b] = lps;          // logp_sum
    }
}

extern "C" void kernel_launch(void* const* d_in, const int* in_sizes, int n_in,
                              void* d_out, int out_size, void* d_ws, size_t ws_size,
                              hipStream_t stream) {
    const float* x    = (const float*)d_in[0];
    const int* lens   = (const int*)  d_in[1];
    const float* emb  = (const float*)d_in[2];
    const float* Wih  = (const float*)d_in[3];
    const float* Whh  = (const float*)d_in[4];
    const float* bih  = (const float*)d_in[5];
    const float* bhh  = (const float*)d_in[6];
    const float* Wj   = (const float*)d_in[7];
    const float* bj   = (const float*)d_in[8];
    float* out = (float*)d_out;
    float* ws  = (float*)d_ws;

    float* E    = ws + E_OFF;
    float* P    = ws + P_OFF;
    u64*   xchg = (u64*)(ws + X_OFF);

    hipLaunchKernelGGL(k_enc,  dim3(1024), dim3(256), 0, stream, x, Wj, bj, E, xchg);
    hipLaunchKernelGGL(k_pred, dim3(29),   dim3(256), 0, stream, emb, Wih, bih, bhh, P);
    hipLaunchKernelGGL(k_dec,  dim3(256),  dim3(256), 0, stream,
                       lens, Whh, Wj, E, P, xchg, out);
}

// Round 11
// 1807.888 us; speedup vs baseline: 1.0089x; 1.0089x over previous
//
#include <hip/hip_runtime.h>
#include <math.h>

typedef unsigned long long u64;
typedef unsigned int u32;

#define BN 32
#define TN 128
#define ENCD 1024
#define HID 320
#define NG 1280       // 4*HID
#define VN 29
#define BLANKI 28
#define SLICES 8
#define UPS 40        // hidden units per slice
#define ROWS 160      // gate rows per slice (4*UPS)
#define JW 1344       // ENC+HID
#define JSTR 41       // padded LDS stride for own-slice joint weights
#define XSTRIDE 70    // u64 words per (parity,b,slice) region; 69 used
#define NPOLL (7*69)  // 483 words polled per step

// workspace layout (floats, then u64 area at X_OFF)
#define E_OFF   0
#define E_SZ    (TN*BN*VN)          // 118784
#define P_OFF   (E_OFF + E_SZ)
#define P_SZ    (VN*NG)             // 37120
#define X_OFF   (P_OFF + P_SZ)      // byte 623616, 16B aligned
// u64 indices within xchg:
#define X_U64S  (2*BN*SLICES*XSTRIDE)      // 35840 (exchange, dbl-buffered)
#define TOK_OFF X_U64S                     // probe tokens, 128B apart
#define HS_OFF  (TOK_OFF + BN*SLICES*16)   // 39936: XCC ids (agent)
#define OK_OFF  (HS_OFF + BN*SLICES)       // 40192: votes (agent)
#define TOTAL_U64S (OK_OFF + BN*SLICES)    // 40448

__device__ __forceinline__ float dot4(float4 a, float4 b) {
    return a.x*b.x + a.y*b.y + a.z*b.z + a.w*b.w;
}
__device__ __forceinline__ u64 aload(const u64* p) {
    return __hip_atomic_load(p, __ATOMIC_RELAXED, __HIP_MEMORY_SCOPE_AGENT);
}
__device__ __forceinline__ void astore(u64* p, u64 v) {
    __hip_atomic_store(p, v, __ATOMIC_RELAXED, __HIP_MEMORY_SCOPE_AGENT);
}
// fast path: plain store (write-through L0 -> home-XCD L2)
__device__ __forceinline__ void pstore(u64* p, u64 v) {
    asm volatile("global_store_dwordx2 %0, %1, off" :: "v"(p), "v"(v) : "memory");
}
// fast path: nt load (bypass L0, read shared XCD L2)
__device__ __forceinline__ u64 ntload(const u64* p) {
    u64 r;
    asm volatile("global_load_dwordx2 %0, %1, off nt\n\ts_waitcnt vmcnt(0)"
                 : "=v"(r) : "v"(p) : "memory");
    return r;
}
__device__ __forceinline__ void xstore(u64* p, u64 v, bool fast) {
    if (fast) pstore(p, v); else astore(p, v);
}
__device__ __forceinline__ u64 xload(const u64* p, bool fast) {
    return fast ? ntload(p) : aload(p);
}

// K1: E[t][b][v] = b_joint[v] + x[t][b][:1024] . W_joint[v][:1024]; zeroes u64 area.
__global__ __launch_bounds__(256) void k_enc(const float* __restrict__ x,
        const float* __restrict__ Wj, const float* __restrict__ bj,
        float* __restrict__ E, u64* __restrict__ xchg)
{
    __shared__ float xl[4][1056];
    const int tid = threadIdx.x;
    const int blk = blockIdx.x;
    const int t = blk >> 3, b0 = (blk & 7) * 4;

    if (tid < 40) {
        const int idx = blk*40 + tid;
        if (idx < TOTAL_U64S) xchg[idx] = 0ull;
    }

    #pragma unroll
    for (int bb = 0; bb < 4; ++bb) {
        const float4* src = (const float4*)(x + ((size_t)(t*BN + b0 + bb))*ENCD);
        float4 v4 = src[tid];
        ((float4*)&xl[bb][0])[tid + (tid >> 5)] = v4;
    }
    __syncthreads();
    if (tid < 232) {
        const int v = tid >> 3, k8 = tid & 7;
        float a0=0.f, a1=0.f, a2=0.f, a3=0.f;
        const float4* wrow = (const float4*)(Wj + (size_t)v*JW) + k8*32;
        const float4* x0 = ((const float4*)&xl[0][0]) + k8*33;
        const float4* x1 = ((const float4*)&xl[1][0]) + k8*33;
        const float4* x2 = ((const float4*)&xl[2][0]) + k8*33;
        const float4* x3 = ((const float4*)&xl[3][0]) + k8*33;
        #pragma unroll 4
        for (int m = 0; m < 32; ++m) {
            float4 w4 = wrow[m];
            a0 += dot4(w4, x0[m]);
            a1 += dot4(w4, x1[m]);
            a2 += dot4(w4, x2[m]);
            a3 += dot4(w4, x3[m]);
        }
        #pragma unroll
        for (int d = 1; d < 8; d <<= 1) {
            a0 += __shfl_xor(a0, d); a1 += __shfl_xor(a1, d);
            a2 += __shfl_xor(a2, d); a3 += __shfl_xor(a3, d);
        }
        if (k8 == 0) {
            float bjv = bj[v];
            E[((size_t)(t*BN + b0+0))*VN + v] = a0 + bjv;
            E[((size_t)(t*BN + b0+1))*VN + v] = a1 + bjv;
            E[((size_t)(t*BN + b0+2))*VN + v] = a2 + bjv;
            E[((size_t)(t*BN + b0+3))*VN + v] = a3 + bjv;
        }
    }
}

// K2: P[j][g] = b_ih[g]+b_hh[g] + emb[j] . W_ih[g]  (j==28 -> bias only / SOS)
__global__ __launch_bounds__(256) void k_pred(const float* __restrict__ emb,
        const float* __restrict__ Wih, const float* __restrict__ bih,
        const float* __restrict__ bhh, float* __restrict__ P)
{
    __shared__ float el[HID];
    const int tid = threadIdx.x, j = blockIdx.x;
    if (tid < 80) {
        float4 v4 = make_float4(0.f, 0.f, 0.f, 0.f);
        if (j < 28) v4 = ((const float4*)(emb + (size_t)j*HID))[tid];
        ((float4*)el)[tid] = v4;
    }
    __syncthreads();
    #pragma unroll
    for (int q = 0; q < 5; ++q) {
        const int r = q*256 + tid;
        float acc = bih[r] + bhh[r];
        const float4* wrow = (const float4*)(Wih + (size_t)r*HID);
        #pragma unroll 8
        for (int k4 = 0; k4 < 80; ++k4)
            acc += dot4(wrow[k4], ((const float4*)el)[k4]);
        P[(size_t)j*NG + r] = acc;
    }
}

// K3: greedy decode (r7 structure). 8 WGs per batch element; tagged exchange.
// Fast medium = plain-store + nt-load through the shared same-XCD L2, enabled
// only if a 2-phase staleness probe passes on ALL slices (unanimous vote);
// otherwise the proven agent-scope path.
__global__ __launch_bounds__(256, 1) void k_dec(const int* __restrict__ lengths,
        const float* __restrict__ Whh, const float* __restrict__ Wj,
        const float* __restrict__ E, const float* __restrict__ P,
        u64* __restrict__ xchg, float* __restrict__ out)
{
    __shared__ float P_lds[VN*ROWS];    // 18560 B
    __shared__ float Wjh[VN*JSTR];      //  4756 B (own-slice joint weights, padded)
    __shared__ float h2st[HID];
    __shared__ float c2st[UPS];
    __shared__ float gates[ROWS];
    __shared__ float plog_l[SLICES*VN];
    __shared__ int   xccok, flag_fast;
    __shared__ int   okv1[8], okv2[8];
    __shared__ float pad_force[14300];  // total LDS > 80KB -> 1 WG/CU

    const int tid = threadIdx.x;
    const int bid = blockIdx.x;
    const int b = bid & 31, slice = bid >> 5;
    const int rg = tid >> 3, kg = tid & 7;
    const int lane = tid & 63;

    // publish own XCC id ASAP (agent scope; overlaps init)
    if (tid == 0) {
        u32 xcc;
        asm volatile("s_getreg_b32 %0, hwreg(HW_REG_XCC_ID)" : "=s"(xcc));
        astore(&xchg[HS_OFF + b*SLICES + slice], (u64)(xcc & 0xFFu) | 0x100ull);
    }

    int len = lengths[b];
    if (len > TN) len = TN;
    if (len < 0) {  // never true; keeps pad_force allocated
        pad_force[tid] = (float)tid;
        gates[tid & 127] = pad_force[(tid*7) & 14299];
    }

    // --- W_hh slice into registers: 5 rows x 40 cols per thread ---
    float4 wq[50];
    #pragma unroll
    for (int q = 0; q < 5; ++q) {
        const int r = rg*5 + q;
        const int gt = r / 40, u = r - gt*40;
        const float4* wrow = (const float4*)(Whh + ((size_t)(gt*HID + slice*UPS + u))*HID + kg*40);
        #pragma unroll
        for (int jb = 0; jb < 10; ++jb) wq[q*10 + jb] = wrow[jb];
    }
    for (int i = tid; i < VN*ROWS; i += 256) {
        const int jj = i / ROWS, r = i - jj*ROWS;
        const int gt = r / 40, u = r - gt*40;
        P_lds[i] = P[(size_t)jj*NG + gt*HID + slice*UPS + u];
    }
    for (int i = tid; i < VN*UPS; i += 256) {
        const int v = i / UPS, k = i - v*UPS;
        Wjh[v*JSTR + k] = Wj[(size_t)v*JW + ENCD + slice*UPS + k];
    }
    if (tid < UPS) c2st[tid] = 0.f;
    if (slice == 0) for (int i = tid; i < 512; i += 256) out[b*512 + i] = -1.0f;
    if (tid < 8) { okv1[tid] = 1; okv2[tid] = 1; }

    // ---- XCC uniformity check ----
    if (tid == 0) {
        bool ok = true; u32 x0 = 0;
        for (int j = 0; j < SLICES; ++j) {
            u64 v = 0; int cap = 0;
            do { v = aload(&xchg[HS_OFF + b*SLICES + j]); }
            while (!(v & 0x100ull) && ++cap < (1 << 22));
            if (!(v & 0x100ull)) { ok = false; break; }
            const u32 xv = (u32)(v & 0xFFu);
            if (xv >= 8u) { ok = false; break; }
            if (j == 0) x0 = xv; else if (xv != x0) { ok = false; break; }
        }
        xccok = ok ? 1 : 0;
    }
    __syncthreads();

    // ---- 2-phase staleness probe through the fast medium ----
    u64* mytok = &xchg[TOK_OFF + (size_t)(b*SLICES + slice)*16];
    if (tid == 0) pstore(mytok, 1ull);
    if (tid < 8 && tid != slice && xccok) {
        const u64* pt = &xchg[TOK_OFF + (size_t)(b*SLICES + tid)*16];
        u64 v = 0; int cap = 0;
        do { v = ntload(pt); } while (v < 1ull && ++cap < (1 << 12));
        if (v < 1ull) okv1[tid] = 0;
    }
    __syncthreads();
    if (tid == 0) pstore(mytok, 2ull);   // update an already-polled line
    if (tid < 8 && tid != slice && xccok) {
        const u64* pt = &xchg[TOK_OFF + (size_t)(b*SLICES + tid)*16];
        u64 v = 0; int cap = 0;
        do { v = ntload(pt); } while (v < 2ull && ++cap < (1 << 12));
        if (v < 2ull) okv2[tid] = 0;
    }
    __syncthreads();
    if (tid == 0) {
        bool ok = (xccok != 0);
        for (int j = 0; j < 8; ++j) ok = ok && okv1[j] && okv2[j];
        astore(&xchg[OK_OFF + b*SLICES + slice], ok ? 3ull : 2ull);
        bool allok = true;
        for (int j = 0; j < SLICES; ++j) {
            u64 v = 0; int cap = 0;
            do { v = aload(&xchg[OK_OFF + b*SLICES + j]); }
            while (v < 2ull && ++cap < (1 << 22));
            if (v != 3ull) allok = false;
        }
        flag_fast = allok ? 1 : 0;
    }
    __syncthreads();
    const bool fast = (flag_fast != 0);

    float lps = 0.f;
    float acc[5] = {0.f, 0.f, 0.f, 0.f, 0.f};   // = W_hh . h  (h starts at 0)
    float lsum_r = 0.f;                          // per-lane joint hidden sum
    int pos = 0, jrow = 28, n = 1;    // full-step sequence (0 = invalid tag)
    bool dirty = true;

    // poll word assignment (fixed per thread): i1 = tid, i2 = tid + 256
    const int pw1 = tid;
    const bool has2 = (tid < NPOLL - 256);       // 227 threads carry a 2nd word

    for (int t = 0; t < len; ++t) {
        const float Ereg = (lane < VN)
            ? E[((size_t)(t*BN + b))*VN + lane] : -INFINITY;

        for (int s = 0; s < 4; ++s) {
            if (dirty) {
                // ================= FULL STEP =================
                const int par = n & 1;
                const size_t mybase = ((size_t)(par*BN + b)*SLICES + slice)*XSTRIDE;
                // gates = cached acc + P[jrow]
                if (kg == 0) {
                    #pragma unroll
                    for (int q = 0; q < 5; ++q) {
                        const int r = rg*5 + q;
                        gates[r] = acc[q] + P_lds[jrow*ROWS + r];
                    }
                }
                __syncthreads();   // B_gates
                if (tid < 64) {
                    // ---------- publisher wave ----------
                    if (tid < UPS) {
                        const float gi = gates[tid],      gf = gates[40+tid];
                        const float gg = gates[80+tid],   go = gates[120+tid];
                        const float ii = 1.f/(1.f+expf(-gi));
                        const float ff = 1.f/(1.f+expf(-gf));
                        const float oo = 1.f/(1.f+expf(-go));
                        const float G  = tanhf(gg);
                        const float c2 = ff*c2st[tid] + ii*G;
                        c2st[tid] = c2;
                        const float h2 = oo * tanhf(c2);
                        h2st[slice*UPS + tid] = h2;
                        const u64 pk = ((u64)(u32)n << 32) | (u64)__float_as_uint(h2);
                        xstore(&xchg[mybase + tid], pk, fast);
                    }
                    // own joint partial from LDS h2 (same-wave ds ordering)
                    if (tid < VN) {
                        float pkv[8];
                        #pragma unroll
                        for (int k8 = 0; k8 < 8; ++k8) {
                            float pk = 0.f;
                            #pragma unroll
                            for (int m2 = 0; m2 < 5; ++m2)
                                pk += Wjh[tid*JSTR + k8*5 + m2]
                                    * h2st[slice*UPS + k8*5 + m2];
                            pkv[k8] = pk;
                        }
                        const float pp = ((pkv[0]+pkv[1])+(pkv[2]+pkv[3]))
                                       + ((pkv[4]+pkv[5])+(pkv[6]+pkv[7]));
                        plog_l[slice*VN + tid] = pp;
                        const u64 pk2 = ((u64)(u32)n << 32) | (u64)__float_as_uint(pp);
                        xstore(&xchg[mybase + UPS + tid], pk2, fast);
                    }
                }
                // ---------- ALL threads poll (plain sampling) ----------
                {
                    const size_t pbase = ((size_t)(par*BN + b)*SLICES)*XSTRIDE;
                    int j1 = pw1 / 69; const int w1 = pw1 - j1*69;
                    j1 += (j1 >= slice);
                    u64* p1 = (u64*)&xchg[pbase + (size_t)j1*XSTRIDE + w1];
                    bool need1 = true, need2 = has2;
                    int j2 = 0, w2 = 0; u64* p2 = p1;
                    if (has2) {
                        const int i2 = tid + 256;
                        j2 = i2 / 69; w2 = i2 - j2*69;
                        j2 += (j2 >= slice);
                        p2 = (u64*)&xchg[pbase + (size_t)j2*XSTRIDE + w2];
                    }
                    int cap = 0;
                    while ((need1 | need2) && cap < (1 << 16)) {
                        u64 v1 = 0, v2 = 0;
                        if (need1) v1 = xload(p1, fast);
                        if (need2) v2 = xload(p2, fast);
                        if (need1 && (u32)(v1 >> 32) == (u32)n) {
                            const float f = __uint_as_float((u32)v1);
                            if (w1 < UPS) h2st[j1*UPS + w1] = f;
                            else          plog_l[j1*VN + (w1 - UPS)] = f;
                            need1 = false;
                        }
                        if (need2 && (u32)(v2 >> 32) == (u32)n) {
                            const float f = __uint_as_float((u32)v2);
                            if (w2 < UPS) h2st[j2*UPS + w2] = f;
                            else          plog_l[j2*VN + (w2 - UPS)] = f;
                            need2 = false;
                        }
                        ++cap;
                    }
                }
                __syncthreads();   // B_poll: full h2st + plog_l ready
                // ---- speculative matvec for the NEXT full step ----
                {
                    float a2[5] = {0.f, 0.f, 0.f, 0.f, 0.f};
                    #pragma unroll
                    for (int jb = 0; jb < 10; ++jb) {
                        float4 hv = *(const float4*)(h2st + kg*40 + jb*4);
                        #pragma unroll
                        for (int q = 0; q < 5; ++q) a2[q] += dot4(wq[q*10 + jb], hv);
                    }
                    #pragma unroll
                    for (int q = 0; q < 5; ++q) {
                        a2[q] += __shfl_xor(a2[q], 1);
                        a2[q] += __shfl_xor(a2[q], 2);
                        a2[q] += __shfl_xor(a2[q], 4);
                        acc[q] = a2[q];
                    }
                }
                // ---- lsum to register (cached across blank steps) ----
                if (lane < VN) {
                    float sA = 0.f;
                    #pragma unroll
                    for (int j2 = 0; j2 < SLICES; ++j2) sA += plog_l[j2*VN + lane];
                    lsum_r = sA;
                }
                n++;
            }
            // ============ logits -> argmax -> update ============
            const float Lv = (lane < VN) ? (Ereg + lsum_r) : -INFINITY;
            float m = Lv; int ai = lane;
            #pragma unroll
            for (int d = 1; d < 64; d <<= 1) {
                const float om = __shfl_xor(m, d);
                const int   oi = __shfl_xor(ai, d);
                if (om > m || (om == m && oi < ai)) { m = om; ai = oi; }
            }
            float e = (lane < VN) ? expf(Lv - m) : 0.f;
            #pragma unroll
            for (int d = 1; d < 64; d <<= 1) e += __shfl_xor(e, d);
            lps += -logf(e);                 // v = logits[argmax] - lse

            if (ai == BLANKI) { dirty = false; break; }
            if (slice == 0 && tid == 0) out[b*512 + pos] = (float)ai;
            pos++;
            jrow = ai;
            dirty = true;
        }
    }

    if (slice == 0 && tid == 0) {
        out[16384 + b] = (float)pos;   // n_symbols
        out[16416 + b] = lps;          // logp_sum
    }
}

extern "C" void kernel_launch(void* const* d_in, const int* in_sizes, int n_in,
                              void* d_out, int out_size, void* d_ws, size_t ws_size,
                              hipStream_t stream) {
    const float* x    = (const float*)d_in[0];
    const int* lens   = (const int*)  d_in[1];
    const float* emb  = (const float*)d_in[2];
    const float* Wih  = (const float*)d_in[3];
    const float* Whh  = (const float*)d_in[4];
    const float* bih  = (const float*)d_in[5];
    const float* bhh  = (const float*)d_in[6];
    const float* Wj   = (const float*)d_in[7];
    const float* bj   = (const float*)d_in[8];
    float* out = (float*)d_out;
    float* ws  = (float*)d_ws;

    float* E    = ws + E_OFF;
    float* P    = ws + P_OFF;
    u64*   xchg = (u64*)(ws + X_OFF);

    hipLaunchKernelGGL(k_enc,  dim3(1024), dim3(256), 0, stream, x, Wj, bj, E, xchg);
    hipLaunchKernelGGL(k_pred, dim3(29),   dim3(256), 0, stream, emb, Wih, bih, bhh, P);
    hipLaunchKernelGGL(k_dec,  dim3(256),  dim3(256), 0, stream,
                       lens, Whh, Wj, E, P, xchg, out);
}

// Round 14
// 1735.123 us; speedup vs baseline: 1.0512x; 1.0419x over previous
//
#include <hip/hip_runtime.h>
#include <math.h>

typedef unsigned long long u64;
typedef unsigned int u32;

#define BN 32
#define TN 128
#define ENCD 1024
#define HID 320
#define NG 1280       // 4*HID
#define VN 29
#define BLANKI 28
#define SLICES 8
#define UPS 40        // hidden units per slice
#define ROWS 160      // gate rows per slice (4*UPS)
#define JW 1344       // ENC+HID
#define JSTR 41       // padded LDS stride for own-slice joint weights
#define XSTRIDE 70    // u64 words per (parity,b,slice) region; 69 used
#define NPOLL (7*69)  // 483 words polled per step

// workspace layout (floats)
#define E_OFF   0
#define E_SZ    (TN*BN*VN)          // 118784
#define P_OFF   (E_OFF + E_SZ)
#define P_SZ    (VN*NG)             // 37120
#define X_OFF   (P_OFF + P_SZ)      // byte 623616, 8B aligned
#define X_U64S  (2*BN*SLICES*XSTRIDE)   // 35840 u64

__device__ __forceinline__ float dot4(float4 a, float4 b) {
    return a.x*b.x + a.y*b.y + a.z*b.z + a.w*b.w;
}
__device__ __forceinline__ u64 aload(const u64* p) {
    return __hip_atomic_load(p, __ATOMIC_RELAXED, __HIP_MEMORY_SCOPE_AGENT);
}
__device__ __forceinline__ void astore(u64* p, u64 v) {
    __hip_atomic_store(p, v, __ATOMIC_RELAXED, __HIP_MEMORY_SCOPE_AGENT);
}

// K1: E[t][b][v] = b_joint[v] + x[t][b][:1024] . W_joint[v][:1024]; zeroes xchg.
__global__ __launch_bounds__(256) void k_enc(const float* __restrict__ x,
        const float* __restrict__ Wj, const float* __restrict__ bj,
        float* __restrict__ E, u64* __restrict__ xchg)
{
    __shared__ float xl[4][1056];
    const int tid = threadIdx.x;
    const int blk = blockIdx.x;
    const int t = blk >> 3, b0 = (blk & 7) * 4;

    if (tid < 35) xchg[(size_t)blk*35 + tid] = 0ull;   // 1024*35 == X_U64S

    #pragma unroll
    for (int bb = 0; bb < 4; ++bb) {
        const float4* src = (const float4*)(x + ((size_t)(t*BN + b0 + bb))*ENCD);
        float4 v4 = src[tid];
        ((float4*)&xl[bb][0])[tid + (tid >> 5)] = v4;
    }
    __syncthreads();
    if (tid < 232) {
        const int v = tid >> 3, k8 = tid & 7;
        float a0=0.f, a1=0.f, a2=0.f, a3=0.f;
        const float4* wrow = (const float4*)(Wj + (size_t)v*JW) + k8*32;
        const float4* x0 = ((const float4*)&xl[0][0]) + k8*33;
        const float4* x1 = ((const float4*)&xl[1][0]) + k8*33;
        const float4* x2 = ((const float4*)&xl[2][0]) + k8*33;
        const float4* x3 = ((const float4*)&xl[3][0]) + k8*33;
        #pragma unroll 4
        for (int m = 0; m < 32; ++m) {
            float4 w4 = wrow[m];
            a0 += dot4(w4, x0[m]);
            a1 += dot4(w4, x1[m]);
            a2 += dot4(w4, x2[m]);
            a3 += dot4(w4, x3[m]);
        }
        #pragma unroll
        for (int d = 1; d < 8; d <<= 1) {
            a0 += __shfl_xor(a0, d); a1 += __shfl_xor(a1, d);
            a2 += __shfl_xor(a2, d); a3 += __shfl_xor(a3, d);
        }
        if (k8 == 0) {
            float bjv = bj[v];
            E[((size_t)(t*BN + b0+0))*VN + v] = a0 + bjv;
            E[((size_t)(t*BN + b0+1))*VN + v] = a1 + bjv;
            E[((size_t)(t*BN + b0+2))*VN + v] = a2 + bjv;
            E[((size_t)(t*BN + b0+3))*VN + v] = a3 + bjv;
        }
    }
}

// K2: P[j][g] = b_ih[g]+b_hh[g] + emb[j] . W_ih[g]  (j==28 -> bias only / SOS)
__global__ __launch_bounds__(256) void k_pred(const float* __restrict__ emb,
        const float* __restrict__ Wih, const float* __restrict__ bih,
        const float* __restrict__ bhh, float* __restrict__ P)
{
    __shared__ float el[HID];
    const int tid = threadIdx.x, j = blockIdx.x;
    if (tid < 80) {
        float4 v4 = make_float4(0.f, 0.f, 0.f, 0.f);
        if (j < 28) v4 = ((const float4*)(emb + (size_t)j*HID))[tid];
        ((float4*)el)[tid] = v4;
    }
    __syncthreads();
    #pragma unroll
    for (int q = 0; q < 5; ++q) {
        const int r = q*256 + tid;
        float acc = bih[r] + bhh[r];
        const float4* wrow = (const float4*)(Wih + (size_t)r*HID);
        #pragma unroll 8
        for (int k4 = 0; k4 < 80; ++k4)
            acc += dot4(wrow[k4], ((const float4*)el)[k4]);
        P[(size_t)j*NG + r] = acc;
    }
}

// pin all 4 scalar components of a float4 (scalar +v ties are supported);
// NOTE: macro parameter must NOT be named x/y/z/w (member-name capture).
#define PIN4(a_) asm volatile("" : "+v"(a_.x), "+v"(a_.y), "+v"(a_.z), "+v"(a_.w))

// K3: greedy decode (r7 structure, agent-scope tagged exchange).
// v14 = r13 with fixed PIN4 macro: W_hh slice held in 50 NAMED float4 locals
// whose scalars are pinned so the compiler cannot re-materialize the loads
// inside the step loop. Everything else is bit-identical to r7.
__global__ __launch_bounds__(256, 1) void k_dec(const int* __restrict__ lengths,
        const float* __restrict__ Whh, const float* __restrict__ Wj,
        const float* __restrict__ E, const float* __restrict__ P,
        u64* __restrict__ xchg, float* __restrict__ out)
{
    __shared__ float P_lds[VN*ROWS];    // 18560 B
    __shared__ float Wjh[VN*JSTR];      //  4756 B (own-slice joint weights, padded)
    __shared__ float h2st[HID];
    __shared__ float c2st[UPS];
    __shared__ float gates[ROWS];
    __shared__ float plog_l[SLICES*VN];
    __shared__ float pad_force[14400];  // total LDS > 80KB -> 1 WG/CU

    const int tid = threadIdx.x;
    const int bid = blockIdx.x;
    const int b = bid & 31, slice = bid >> 5;
    const int rg = tid >> 3, kg = tid & 7;
    const int lane = tid & 63;

    int len = lengths[b];
    if (len > TN) len = TN;
    if (len < 0) {  // never true; keeps pad_force allocated
        pad_force[tid] = (float)tid;
        gates[tid & 127] = pad_force[(tid*7) & 14399];
    }

    // --- W_hh slice: 5 rows x 40 cols per thread, in 50 named pinned regs ---
    const float4* wb0; const float4* wb1; const float4* wb2;
    const float4* wb3; const float4* wb4;
    {
        const float4* wbt[5];
        #pragma unroll
        for (int q = 0; q < 5; ++q) {
            const int r = rg*5 + q;
            const int gt = r / 40, u = r - gt*40;
            wbt[q] = (const float4*)(Whh + ((size_t)(gt*HID + slice*UPS + u))*HID + kg*40);
        }
        wb0 = wbt[0]; wb1 = wbt[1]; wb2 = wbt[2]; wb3 = wbt[3]; wb4 = wbt[4];
    }
    float4 w00=wb0[0], w01=wb0[1], w02=wb0[2], w03=wb0[3], w04=wb0[4];
    float4 w05=wb0[5], w06=wb0[6], w07=wb0[7], w08=wb0[8], w09=wb0[9];
    float4 w10=wb1[0], w11=wb1[1], w12=wb1[2], w13=wb1[3], w14=wb1[4];
    float4 w15=wb1[5], w16=wb1[6], w17=wb1[7], w18=wb1[8], w19=wb1[9];
    float4 w20=wb2[0], w21=wb2[1], w22=wb2[2], w23=wb2[3], w24=wb2[4];
    float4 w25=wb2[5], w26=wb2[6], w27=wb2[7], w28=wb2[8], w29=wb2[9];
    float4 w30=wb3[0], w31=wb3[1], w32=wb3[2], w33=wb3[3], w34=wb3[4];
    float4 w35=wb3[5], w36=wb3[6], w37=wb3[7], w38=wb3[8], w39=wb3[9];
    float4 w40=wb4[0], w41=wb4[1], w42=wb4[2], w43=wb4[3], w44=wb4[4];
    float4 w45=wb4[5], w46=wb4[6], w47=wb4[7], w48=wb4[8], w49=wb4[9];
    PIN4(w00); PIN4(w01); PIN4(w02); PIN4(w03); PIN4(w04);
    PIN4(w05); PIN4(w06); PIN4(w07); PIN4(w08); PIN4(w09);
    PIN4(w10); PIN4(w11); PIN4(w12); PIN4(w13); PIN4(w14);
    PIN4(w15); PIN4(w16); PIN4(w17); PIN4(w18); PIN4(w19);
    PIN4(w20); PIN4(w21); PIN4(w22); PIN4(w23); PIN4(w24);
    PIN4(w25); PIN4(w26); PIN4(w27); PIN4(w28); PIN4(w29);
    PIN4(w30); PIN4(w31); PIN4(w32); PIN4(w33); PIN4(w34);
    PIN4(w35); PIN4(w36); PIN4(w37); PIN4(w38); PIN4(w39);
    PIN4(w40); PIN4(w41); PIN4(w42); PIN4(w43); PIN4(w44);
    PIN4(w45); PIN4(w46); PIN4(w47); PIN4(w48); PIN4(w49);

    for (int i = tid; i < VN*ROWS; i += 256) {
        const int jj = i / ROWS, r = i - jj*ROWS;
        const int gt = r / 40, u = r - gt*40;
        P_lds[i] = P[(size_t)jj*NG + gt*HID + slice*UPS + u];
    }
    // own-slice joint weights, padded stride 41
    for (int i = tid; i < VN*UPS; i += 256) {
        const int v = i / UPS, k = i - v*UPS;
        Wjh[v*JSTR + k] = Wj[(size_t)v*JW + ENCD + slice*UPS + k];
    }
    if (tid < UPS) c2st[tid] = 0.f;
    if (slice == 0) for (int i = tid; i < 512; i += 256) out[b*512 + i] = -1.0f;
    __syncthreads();

    float lps = 0.f;
    float acc[5] = {0.f, 0.f, 0.f, 0.f, 0.f};   // = W_hh . h  (h starts at 0)
    float lsum_r = 0.f;                          // per-lane joint hidden sum
    int pos = 0, jrow = 28, n = 1;    // full-step sequence (0 = invalid tag)
    bool dirty = true;

    // poll word assignment (fixed per thread): i1 = tid, i2 = tid + 256
    const int pw1 = tid;
    const bool has2 = (tid < NPOLL - 256);       // 227 threads carry a 2nd word

    for (int t = 0; t < len; ++t) {
        const float Ereg = (lane < VN)
            ? E[((size_t)(t*BN + b))*VN + lane] : -INFINITY;

        for (int s = 0; s < 4; ++s) {
            if (dirty) {
                // ================= FULL STEP =================
                const int par = n & 1;
                const size_t mybase = ((size_t)(par*BN + b)*SLICES + slice)*XSTRIDE;
                // gates = cached acc + P[jrow]
                if (kg == 0) {
                    #pragma unroll
                    for (int q = 0; q < 5; ++q) {
                        const int r = rg*5 + q;
                        gates[r] = acc[q] + P_lds[jrow*ROWS + r];
                    }
                }
                __syncthreads();   // B_gates
                if (tid < 64) {
                    // ---------- publisher wave ----------
                    if (tid < UPS) {
                        const float gi = gates[tid],      gf = gates[40+tid];
                        const float gg = gates[80+tid],   go = gates[120+tid];
                        const float ii = 1.f/(1.f+expf(-gi));
                        const float ff = 1.f/(1.f+expf(-gf));
                        const float oo = 1.f/(1.f+expf(-go));
                        const float G  = tanhf(gg);
                        const float c2 = ff*c2st[tid] + ii*G;
                        c2st[tid] = c2;
                        const float h2 = oo * tanhf(c2);
                        h2st[slice*UPS + tid] = h2;
                        const u64 pk = ((u64)(u32)n << 32) | (u64)__float_as_uint(h2);
                        astore(&xchg[mybase + tid], pk);
                    }
                    // own joint partial from LDS h2 (same-wave ds ordering)
                    if (tid < VN) {
                        float pkv[8];
                        #pragma unroll
                        for (int k8 = 0; k8 < 8; ++k8) {
                            float pk = 0.f;
                            #pragma unroll
                            for (int m2 = 0; m2 < 5; ++m2)
                                pk += Wjh[tid*JSTR + k8*5 + m2]
                                    * h2st[slice*UPS + k8*5 + m2];
                            pkv[k8] = pk;
                        }
                        const float pp = ((pkv[0]+pkv[1])+(pkv[2]+pkv[3]))
                                       + ((pkv[4]+pkv[5])+(pkv[6]+pkv[7]));
                        plog_l[slice*VN + tid] = pp;
                        const u64 pk2 = ((u64)(u32)n << 32) | (u64)__float_as_uint(pp);
                        astore(&xchg[mybase + UPS + tid], pk2);
                    }
                }
                // ---------- ALL threads poll (plain sampling) ----------
                {
                    const size_t pbase = ((size_t)(par*BN + b)*SLICES)*XSTRIDE;
                    int j1 = pw1 / 69; const int w1 = pw1 - j1*69;
                    j1 += (j1 >= slice);
                    u64* p1 = (u64*)&xchg[pbase + (size_t)j1*XSTRIDE + w1];
                    bool need1 = true, need2 = has2;
                    int j2 = 0, w2 = 0; u64* p2 = p1;
                    if (has2) {
                        const int i2 = tid + 256;
                        j2 = i2 / 69; w2 = i2 - j2*69;
                        j2 += (j2 >= slice);
                        p2 = (u64*)&xchg[pbase + (size_t)j2*XSTRIDE + w2];
                    }
                    int cap = 0;
                    while ((need1 | need2) && cap < (1 << 16)) {
                        u64 v1 = 0, v2 = 0;
                        if (need1) v1 = aload(p1);
                        if (need2) v2 = aload(p2);
                        if (need1 && (u32)(v1 >> 32) == (u32)n) {
                            const float f = __uint_as_float((u32)v1);
                            if (w1 < UPS) h2st[j1*UPS + w1] = f;
                            else          plog_l[j1*VN + (w1 - UPS)] = f;
                            need1 = false;
                        }
                        if (need2 && (u32)(v2 >> 32) == (u32)n) {
                            const float f = __uint_as_float((u32)v2);
                            if (w2 < UPS) h2st[j2*UPS + w2] = f;
                            else          plog_l[j2*VN + (w2 - UPS)] = f;
                            need2 = false;
                        }
                        ++cap;
                    }
                }
                __syncthreads();   // B_poll: full h2st + plog_l ready
                // ---- speculative matvec for the NEXT full step (pinned regs) ----
                {
                    const float4* hvp = (const float4*)(h2st + kg*40);
                    float a20 = 0.f, a21 = 0.f, a22 = 0.f, a23 = 0.f, a24 = 0.f;
                    #define MV(JB, WA, WB, WC, WD, WE)                      \
                        { const float4 hv = hvp[JB];                        \
                          a20 += dot4(WA, hv); a21 += dot4(WB, hv);         \
                          a22 += dot4(WC, hv); a23 += dot4(WD, hv);         \
                          a24 += dot4(WE, hv); }
                    MV(0, w00, w10, w20, w30, w40)
                    MV(1, w01, w11, w21, w31, w41)
                    MV(2, w02, w12, w22, w32, w42)
                    MV(3, w03, w13, w23, w33, w43)
                    MV(4, w04, w14, w24, w34, w44)
                    MV(5, w05, w15, w25, w35, w45)
                    MV(6, w06, w16, w26, w36, w46)
                    MV(7, w07, w17, w27, w37, w47)
                    MV(8, w08, w18, w28, w38, w48)
                    MV(9, w09, w19, w29, w39, w49)
                    #undef MV
                    float a2[5] = {a20, a21, a22, a23, a24};
                    #pragma unroll
                    for (int q = 0; q < 5; ++q) {
                        a2[q] += __shfl_xor(a2[q], 1);
                        a2[q] += __shfl_xor(a2[q], 2);
                        a2[q] += __shfl_xor(a2[q], 4);
                        acc[q] = a2[q];
                    }
                }
                // ---- lsum to register (cached across blank steps) ----
                if (lane < VN) {
                    float sA = 0.f;
                    #pragma unroll
                    for (int j2 = 0; j2 < SLICES; ++j2) sA += plog_l[j2*VN + lane];
                    lsum_r = sA;
                }
                n++;
            }
            // ============ logits -> argmax -> update ============
            const float Lv = (lane < VN) ? (Ereg + lsum_r) : -INFINITY;
            float m = Lv; int ai = lane;
            #pragma unroll
            for (int d = 1; d < 64; d <<= 1) {
                const float om = __shfl_xor(m, d);
                const int   oi = __shfl_xor(ai, d);
                if (om > m || (om == m && oi < ai)) { m = om; ai = oi; }
            }
            float e = (lane < VN) ? expf(Lv - m) : 0.f;
            #pragma unroll
            for (int d = 1; d < 64; d <<= 1) e += __shfl_xor(e, d);
            lps += -logf(e);                 // v = logits[argmax] - lse

            if (ai == BLANKI) { dirty = false; break; }
            if (slice == 0 && tid == 0) out[b*512 + pos] = (float)ai;
            pos++;
            jrow = ai;
            dirty = true;
        }
    }

    if (slice == 0 && tid == 0) {
        out[16384 + b] = (float)pos;   // n_symbols
        out[16416 + b] = lps;          // logp_sum
    }
}

extern "C" void kernel_launch(void* const* d_in, const int* in_sizes, int n_in,
                              void* d_out, int out_size, void* d_ws, size_t ws_size,
                              hipStream_t stream) {
    const float* x    = (const float*)d_in[0];
    const int* lens   = (const int*)  d_in[1];
    const float* emb  = (const float*)d_in[2];
    const float* Wih  = (const float*)d_in[3];
    const float* Whh  = (const float*)d_in[4];
    const float* bih  = (const float*)d_in[5];
    const float* bhh  = (const float*)d_in[6];
    const float* Wj   = (const float*)d_in[7];
    const float* bj   = (const float*)d_in[8];
    float* out = (float*)d_out;
    float* ws  = (float*)d_ws;

    float* E    = ws + E_OFF;
    float* P    = ws + P_OFF;
    u64*   xchg = (u64*)(ws + X_OFF);

    hipLaunchKernelGGL(k_enc,  dim3(1024), dim3(256), 0, stream, x, Wj, bj, E, xchg);
    hipLaunchKernelGGL(k_pred, dim3(29),   dim3(256), 0, stream, emb, Wih, bih, bhh, P);
    hipLaunchKernelGGL(k_dec,  dim3(256),  dim3(256), 0, stream,
                       lens, Whh, Wj, E, P, xchg, out);
}

// Round 15
// 1673.521 us; speedup vs baseline: 1.0899x; 1.0368x over previous
//
#include <hip/hip_runtime.h>
#include <math.h>

typedef unsigned long long u64;
typedef unsigned int u32;

#define BN 32
#define TN 128
#define ENCD 1024
#define HID 320
#define NG 1280       // 4*HID
#define VN 29
#define BLANKI 28
#define SLICES 8
#define UPS 40        // hidden units per slice
#define ROWS 160      // gate rows per slice (4*UPS)
#define JW 1344       // ENC+HID
#define JSTR 41       // padded LDS stride for own-slice joint weights
#define XSTRIDE 70    // u64 words per (parity,b,slice) region; 69 used
#define NPOLL (7*69)  // 483 words polled per step

// workspace layout (floats)
#define E_OFF   0
#define E_SZ    (TN*BN*VN)          // 118784
#define P_OFF   (E_OFF + E_SZ)
#define P_SZ    (VN*NG)             // 37120
#define X_OFF   (P_OFF + P_SZ)      // byte 623616, 8B aligned
#define X_U64S  (2*BN*SLICES*XSTRIDE)   // 35840 u64

__device__ __forceinline__ float dot4(float4 a, float4 b) {
    return a.x*b.x + a.y*b.y + a.z*b.z + a.w*b.w;
}
__device__ __forceinline__ u64 aload(const u64* p) {
    return __hip_atomic_load(p, __ATOMIC_RELAXED, __HIP_MEMORY_SCOPE_AGENT);
}
__device__ __forceinline__ void astore(u64* p, u64 v) {
    __hip_atomic_store(p, v, __ATOMIC_RELAXED, __HIP_MEMORY_SCOPE_AGENT);
}

// K1: E[t][b][v] = b_joint[v] + x[t][b][:1024] . W_joint[v][:1024]; zeroes xchg.
__global__ __launch_bounds__(256) void k_enc(const float* __restrict__ x,
        const float* __restrict__ Wj, const float* __restrict__ bj,
        float* __restrict__ E, u64* __restrict__ xchg)
{
    __shared__ float xl[4][1056];
    const int tid = threadIdx.x;
    const int blk = blockIdx.x;
    const int t = blk >> 3, b0 = (blk & 7) * 4;

    if (tid < 35) xchg[(size_t)blk*35 + tid] = 0ull;   // 1024*35 == X_U64S

    #pragma unroll
    for (int bb = 0; bb < 4; ++bb) {
        const float4* src = (const float4*)(x + ((size_t)(t*BN + b0 + bb))*ENCD);
        float4 v4 = src[tid];
        ((float4*)&xl[bb][0])[tid + (tid >> 5)] = v4;
    }
    __syncthreads();
    if (tid < 232) {
        const int v = tid >> 3, k8 = tid & 7;
        float a0=0.f, a1=0.f, a2=0.f, a3=0.f;
        const float4* wrow = (const float4*)(Wj + (size_t)v*JW) + k8*32;
        const float4* x0 = ((const float4*)&xl[0][0]) + k8*33;
        const float4* x1 = ((const float4*)&xl[1][0]) + k8*33;
        const float4* x2 = ((const float4*)&xl[2][0]) + k8*33;
        const float4* x3 = ((const float4*)&xl[3][0]) + k8*33;
        #pragma unroll 4
        for (int m = 0; m < 32; ++m) {
            float4 w4 = wrow[m];
            a0 += dot4(w4, x0[m]);
            a1 += dot4(w4, x1[m]);
            a2 += dot4(w4, x2[m]);
            a3 += dot4(w4, x3[m]);
        }
        #pragma unroll
        for (int d = 1; d < 8; d <<= 1) {
            a0 += __shfl_xor(a0, d); a1 += __shfl_xor(a1, d);
            a2 += __shfl_xor(a2, d); a3 += __shfl_xor(a3, d);
        }
        if (k8 == 0) {
            float bjv = bj[v];
            E[((size_t)(t*BN + b0+0))*VN + v] = a0 + bjv;
            E[((size_t)(t*BN + b0+1))*VN + v] = a1 + bjv;
            E[((size_t)(t*BN + b0+2))*VN + v] = a2 + bjv;
            E[((size_t)(t*BN + b0+3))*VN + v] = a3 + bjv;
        }
    }
}

// K2: P[j][g] = b_ih[g]+b_hh[g] + emb[j] . W_ih[g]  (j==28 -> bias only / SOS)
__global__ __launch_bounds__(256) void k_pred(const float* __restrict__ emb,
        const float* __restrict__ Wih, const float* __restrict__ bih,
        const float* __restrict__ bhh, float* __restrict__ P)
{
    __shared__ float el[HID];
    const int tid = threadIdx.x, j = blockIdx.x;
    if (tid < 80) {
        float4 v4 = make_float4(0.f, 0.f, 0.f, 0.f);
        if (j < 28) v4 = ((const float4*)(emb + (size_t)j*HID))[tid];
        ((float4*)el)[tid] = v4;
    }
    __syncthreads();
    #pragma unroll
    for (int q = 0; q < 5; ++q) {
        const int r = q*256 + tid;
        float acc = bih[r] + bhh[r];
        const float4* wrow = (const float4*)(Wih + (size_t)r*HID);
        #pragma unroll 8
        for (int k4 = 0; k4 < 80; ++k4)
            acc += dot4(wrow[k4], ((const float4*)el)[k4]);
        P[(size_t)j*NG + r] = acc;
    }
}

// pin all 4 scalar components of a float4 (macro param must not be x/y/z/w)
#define PIN4(a_) asm volatile("" : "+v"(a_.x), "+v"(a_.y), "+v"(a_.z), "+v"(a_.w))

// K3: greedy decode (r7 structure, agent-scope tagged exchange).
// v15: W_hh slice split 30 float4/thread -> EXPLICIT LDS (120 KB, element-major,
// conflict-free) + 20 float4/thread -> pinned registers (80 VGPR). Removes
// the per-step 200 KB L2/scratch re-stream the compiler was generating.
// All arithmetic order bit-identical to r7.
__global__ __launch_bounds__(256, 1) void k_dec(const int* __restrict__ lengths,
        const float* __restrict__ Whh, const float* __restrict__ Wj,
        const float* __restrict__ E, const float* __restrict__ P,
        u64* __restrict__ xchg, float* __restrict__ out)
{
    __shared__ float4 wlds[30*256];     // 122880 B : W_hh jb=0..5 portion
    __shared__ float P_lds[VN*ROWS];    //  18560 B
    __shared__ float Wjh[VN*JSTR];      //   4756 B
    __shared__ float h2st[HID];
    __shared__ float c2st[UPS];
    __shared__ float gates[ROWS];
    __shared__ float plog_l[SLICES*VN]; // total ~149.2 KB -> 1 WG/CU guaranteed

    const int tid = threadIdx.x;
    const int bid = blockIdx.x;
    const int b = bid & 31, slice = bid >> 5;
    const int rg = tid >> 3, kg = tid & 7;
    const int lane = tid & 63;

    int len = lengths[b];
    if (len > TN) len = TN;

    // --- W_hh slice: 5 rows x 40 cols per thread.
    //     jb 0..5 -> LDS wlds[(q*6+jb)*256 + tid]; jb 6..9 -> pinned regs. ---
    float4 w06, w07, w08, w09, w16, w17, w18, w19, w26, w27;
    float4 w28, w29, w36, w37, w38, w39, w46, w47, w48, w49;
    {
        const float4* wbt[5];
        #pragma unroll
        for (int q = 0; q < 5; ++q) {
            const int r = rg*5 + q;
            const int gt = r / 40, u = r - gt*40;
            wbt[q] = (const float4*)(Whh + ((size_t)(gt*HID + slice*UPS + u))*HID + kg*40);
        }
        #pragma unroll
        for (int q = 0; q < 5; ++q)
            #pragma unroll
            for (int jb = 0; jb < 6; ++jb)
                wlds[(q*6 + jb)*256 + tid] = wbt[q][jb];
        w06 = wbt[0][6]; w07 = wbt[0][7]; w08 = wbt[0][8]; w09 = wbt[0][9];
        w16 = wbt[1][6]; w17 = wbt[1][7]; w18 = wbt[1][8]; w19 = wbt[1][9];
        w26 = wbt[2][6]; w27 = wbt[2][7]; w28 = wbt[2][8]; w29 = wbt[2][9];
        w36 = wbt[3][6]; w37 = wbt[3][7]; w38 = wbt[3][8]; w39 = wbt[3][9];
        w46 = wbt[4][6]; w47 = wbt[4][7]; w48 = wbt[4][8]; w49 = wbt[4][9];
    }
    PIN4(w06); PIN4(w07); PIN4(w08); PIN4(w09);
    PIN4(w16); PIN4(w17); PIN4(w18); PIN4(w19);
    PIN4(w26); PIN4(w27); PIN4(w28); PIN4(w29);
    PIN4(w36); PIN4(w37); PIN4(w38); PIN4(w39);
    PIN4(w46); PIN4(w47); PIN4(w48); PIN4(w49);

    for (int i = tid; i < VN*ROWS; i += 256) {
        const int jj = i / ROWS, r = i - jj*ROWS;
        const int gt = r / 40, u = r - gt*40;
        P_lds[i] = P[(size_t)jj*NG + gt*HID + slice*UPS + u];
    }
    // own-slice joint weights, padded stride 41
    for (int i = tid; i < VN*UPS; i += 256) {
        const int v = i / UPS, k = i - v*UPS;
        Wjh[v*JSTR + k] = Wj[(size_t)v*JW + ENCD + slice*UPS + k];
    }
    if (tid < UPS) c2st[tid] = 0.f;
    if (slice == 0) for (int i = tid; i < 512; i += 256) out[b*512 + i] = -1.0f;
    __syncthreads();

    float lps = 0.f;
    float acc[5] = {0.f, 0.f, 0.f, 0.f, 0.f};   // = W_hh . h  (h starts at 0)
    float lsum_r = 0.f;                          // per-lane joint hidden sum
    int pos = 0, jrow = 28, n = 1;    // full-step sequence (0 = invalid tag)
    bool dirty = true;

    // poll word assignment (fixed per thread): i1 = tid, i2 = tid + 256
    const int pw1 = tid;
    const bool has2 = (tid < NPOLL - 256);       // 227 threads carry a 2nd word

    for (int t = 0; t < len; ++t) {
        const float Ereg = (lane < VN)
            ? E[((size_t)(t*BN + b))*VN + lane] : -INFINITY;

        for (int s = 0; s < 4; ++s) {
            if (dirty) {
                // ================= FULL STEP =================
                const int par = n & 1;
                const size_t mybase = ((size_t)(par*BN + b)*SLICES + slice)*XSTRIDE;
                // gates = cached acc + P[jrow]
                if (kg == 0) {
                    #pragma unroll
                    for (int q = 0; q < 5; ++q) {
                        const int r = rg*5 + q;
                        gates[r] = acc[q] + P_lds[jrow*ROWS + r];
                    }
                }
                __syncthreads();   // B_gates
                if (tid < 64) {
                    // ---------- publisher wave ----------
                    if (tid < UPS) {
                        const float gi = gates[tid],      gf = gates[40+tid];
                        const float gg = gates[80+tid],   go = gates[120+tid];
                        const float ii = 1.f/(1.f+expf(-gi));
                        const float ff = 1.f/(1.f+expf(-gf));
                        const float oo = 1.f/(1.f+expf(-go));
                        const float G  = tanhf(gg);
                        const float c2 = ff*c2st[tid] + ii*G;
                        c2st[tid] = c2;
                        const float h2 = oo * tanhf(c2);
                        h2st[slice*UPS + tid] = h2;
                        const u64 pk = ((u64)(u32)n << 32) | (u64)__float_as_uint(h2);
                        astore(&xchg[mybase + tid], pk);
                    }
                    // own joint partial from LDS h2 (same-wave ds ordering)
                    if (tid < VN) {
                        float pkv[8];
                        #pragma unroll
                        for (int k8 = 0; k8 < 8; ++k8) {
                            float pk = 0.f;
                            #pragma unroll
                            for (int m2 = 0; m2 < 5; ++m2)
                                pk += Wjh[tid*JSTR + k8*5 + m2]
                                    * h2st[slice*UPS + k8*5 + m2];
                            pkv[k8] = pk;
                        }
                        const float pp = ((pkv[0]+pkv[1])+(pkv[2]+pkv[3]))
                                       + ((pkv[4]+pkv[5])+(pkv[6]+pkv[7]));
                        plog_l[slice*VN + tid] = pp;
                        const u64 pk2 = ((u64)(u32)n << 32) | (u64)__float_as_uint(pp);
                        astore(&xchg[mybase + UPS + tid], pk2);
                    }
                }
                // ---------- ALL threads poll (plain sampling) ----------
                {
                    const size_t pbase = ((size_t)(par*BN + b)*SLICES)*XSTRIDE;
                    int j1 = pw1 / 69; const int w1 = pw1 - j1*69;
                    j1 += (j1 >= slice);
                    u64* p1 = (u64*)&xchg[pbase + (size_t)j1*XSTRIDE + w1];
                    bool need1 = true, need2 = has2;
                    int j2 = 0, w2 = 0; u64* p2 = p1;
                    if (has2) {
                        const int i2 = tid + 256;
                        j2 = i2 / 69; w2 = i2 - j2*69;
                        j2 += (j2 >= slice);
                        p2 = (u64*)&xchg[pbase + (size_t)j2*XSTRIDE + w2];
                    }
                    int cap = 0;
                    while ((need1 | need2) && cap < (1 << 16)) {
                        u64 v1 = 0, v2 = 0;
                        if (need1) v1 = aload(p1);
                        if (need2) v2 = aload(p2);
                        if (need1 && (u32)(v1 >> 32) == (u32)n) {
                            const float f = __uint_as_float((u32)v1);
                            if (w1 < UPS) h2st[j1*UPS + w1] = f;
                            else          plog_l[j1*VN + (w1 - UPS)] = f;
                            need1 = false;
                        }
                        if (need2 && (u32)(v2 >> 32) == (u32)n) {
                            const float f = __uint_as_float((u32)v2);
                            if (w2 < UPS) h2st[j2*UPS + w2] = f;
                            else          plog_l[j2*VN + (w2 - UPS)] = f;
                            need2 = false;
                        }
                        ++cap;
                    }
                }
                __syncthreads();   // B_poll: full h2st + plog_l ready
                // ---- speculative matvec for the NEXT full step ----
                // order identical to r7: jb ascending 0..9, q ascending inside
                {
                    const float4* hvp = (const float4*)(h2st + kg*40);
                    float a2[5] = {0.f, 0.f, 0.f, 0.f, 0.f};
                    #pragma unroll
                    for (int jb = 0; jb < 6; ++jb) {
                        const float4 hv = hvp[jb];
                        #pragma unroll
                        for (int q = 0; q < 5; ++q)
                            a2[q] += dot4(wlds[(q*6 + jb)*256 + tid], hv);
                    }
                    #define MVR(JB, WA, WB, WC, WD, WE)                     \
                        { const float4 hv = hvp[JB];                        \
                          a2[0] += dot4(WA, hv); a2[1] += dot4(WB, hv);     \
                          a2[2] += dot4(WC, hv); a2[3] += dot4(WD, hv);     \
                          a2[4] += dot4(WE, hv); }
                    MVR(6, w06, w16, w26, w36, w46)
                    MVR(7, w07, w17, w27, w37, w47)
                    MVR(8, w08, w18, w28, w38, w48)
                    MVR(9, w09, w19, w29, w39, w49)
                    #undef MVR
                    #pragma unroll
                    for (int q = 0; q < 5; ++q) {
                        a2[q] += __shfl_xor(a2[q], 1);
                        a2[q] += __shfl_xor(a2[q], 2);
                        a2[q] += __shfl_xor(a2[q], 4);
                        acc[q] = a2[q];
                    }
                }
                // ---- lsum to register (cached across blank steps) ----
                if (lane < VN) {
                    float sA = 0.f;
                    #pragma unroll
                    for (int j2 = 0; j2 < SLICES; ++j2) sA += plog_l[j2*VN + lane];
                    lsum_r = sA;
                }
                n++;
            }
            // ============ logits -> argmax -> update ============
            const float Lv = (lane < VN) ? (Ereg + lsum_r) : -INFINITY;
            float m = Lv; int ai = lane;
            #pragma unroll
            for (int d = 1; d < 64; d <<= 1) {
                const float om = __shfl_xor(m, d);
                const int   oi = __shfl_xor(ai, d);
                if (om > m || (om == m && oi < ai)) { m = om; ai = oi; }
            }
            float e = (lane < VN) ? expf(Lv - m) : 0.f;
            #pragma unroll
            for (int d = 1; d < 64; d <<= 1) e += __shfl_xor(e, d);
            lps += -logf(e);                 // v = logits[argmax] - lse

            if (ai == BLANKI) { dirty = false; break; }
            if (slice == 0 && tid == 0) out[b*512 + pos] = (float)ai;
            pos++;
            jrow = ai;
            dirty = true;
        }
    }

    if (slice == 0 && tid == 0) {
        out[16384 + b] = (float)pos;   // n_symbols
        out[16416 + b] = lps;          // logp_sum
    }
}

extern "C" void kernel_launch(void* const* d_in, const int* in_sizes, int n_in,
                              void* d_out, int out_size, void* d_ws, size_t ws_size,
                              hipStream_t stream) {
    const float* x    = (const float*)d_in[0];
    const int* lens   = (const int*)  d_in[1];
    const float* emb  = (const float*)d_in[2];
    const float* Wih  = (const float*)d_in[3];
    const float* Whh  = (const float*)d_in[4];
    const float* bih  = (const float*)d_in[5];
    const float* bhh  = (const float*)d_in[6];
    const float* Wj   = (const float*)d_in[7];
    const float* bj   = (const float*)d_in[8];
    float* out = (float*)d_out;
    float* ws  = (float*)d_ws;

    float* E    = ws + E_OFF;
    float* P    = ws + P_OFF;
    u64*   xchg = (u64*)(ws + X_OFF);

    hipLaunchKernelGGL(k_enc,  dim3(1024), dim3(256), 0, stream, x, Wj, bj, E, xchg);
    hipLaunchKernelGGL(k_pred, dim3(29),   dim3(256), 0, stream, emb, Wih, bih, bhh, P);
    hipLaunchKernelGGL(k_dec,  dim3(256),  dim3(256), 0, stream,
                       lens, Whh, Wj, E, P, xchg, out);
}